// Round 1
// baseline (4564.771 us; speedup 1.0000x reference)
//
#include <hip/hip_runtime.h>
#include <hip/hip_bf16.h>

#define BB 512
#define SS 256
#define HH 256
#define DD 64
#define TT 50
#define GG 1024   // 4*H
#define INW 129
#define INP 132   // padded K for input projection

typedef unsigned short u16;
typedef unsigned int u32;

__device__ inline float bf2f(u16 u) { return __uint_as_float(((u32)u) << 16); }
__device__ inline float4 b4f(ushort4 u) {
    float4 r; r.x = bf2f(u.x); r.y = bf2f(u.y); r.z = bf2f(u.z); r.w = bf2f(u.w); return r;
}
// round-to-nearest-even f32 -> bf16 (finite inputs only)
__device__ inline u16 f2b(float f) {
    u32 x = __float_as_uint(f);
    return (u16)((x + 0x7fffu + ((x >> 16) & 1u)) >> 16);
}
__device__ inline float sigf(float x) { return 1.f / (1.f + __expf(-x)); }
__device__ inline float tanhf_(float x) { return 1.f - 2.f / (__expf(2.f * x) + 1.f); }

// ---------------- prep: pack W_hh^T and W_ih^T as k4-packed bf16 ----------------
// Whh4[k4][g] = {W_hh[g][4k4+0..3]}  (64*1024 ushort4)
// Wih4[k4][g] = {W_ih[g][4k4+0..3]}  (33*1024 ushort4, zero-padded k>=129)
__global__ __launch_bounds__(256) void prep_kernel(
    const float* __restrict__ W_hh, const float* __restrict__ W_ih,
    ushort4* __restrict__ Whh4, ushort4* __restrict__ Wih4)
{
    int idx = blockIdx.x * 256 + threadIdx.x;
    if (idx < 64 * 1024) {
        int k4 = idx >> 10, g = idx & 1023;
        float4 v = *(const float4*)(W_hh + (size_t)g * HH + (k4 << 2));
        Whh4[idx] = make_ushort4(f2b(v.x), f2b(v.y), f2b(v.z), f2b(v.w));
    } else if (idx < 64 * 1024 + 33 * 1024) {
        int j = idx - 64 * 1024;
        int k4 = j >> 10, g = j & 1023;
        float v[4];
#pragma unroll
        for (int e = 0; e < 4; e++) {
            int c = (k4 << 2) + e;
            v[e] = (c < INW) ? W_ih[(size_t)g * INW + c] : 0.f;
        }
        Wih4[j] = make_ushort4(f2b(v[0]), f2b(v[1]), f2b(v[2]), f2b(v[3]));
    }
}

// ---------------- xW = x @ W_ih^T + b_ih + b_hh  -> bf16 [B][S][1024] ----------------
__global__ __launch_bounds__(256) void xw_kernel(
    const float* __restrict__ x, const ushort4* __restrict__ Wih4,
    const float* __restrict__ b_ih, const float* __restrict__ b_hh,
    __hip_bfloat16* __restrict__ xw)
{
    __shared__ __align__(16) float xsh[16][INP];
    int tid = threadIdx.x;
    size_t r0 = (size_t)blockIdx.x * 16;
    for (int i = tid; i < 16 * INP; i += 256) {
        int rr = i / INP, cc = i % INP;
        xsh[rr][cc] = (cc < INW) ? x[(r0 + rr) * INW + cc] : 0.f;
    }
    float bsum[4];
#pragma unroll
    for (int q = 0; q < 4; q++) bsum[q] = b_ih[(q << 8) + tid] + b_hh[(q << 8) + tid];
    __syncthreads();
    float acc[16][4];
#pragma unroll
    for (int r = 0; r < 16; r++) {
        acc[r][0] = bsum[0]; acc[r][1] = bsum[1]; acc[r][2] = bsum[2]; acc[r][3] = bsum[3];
    }
    for (int k4 = 0; k4 < 33; k4++) {
        const ushort4* wp = Wih4 + (k4 << 10);
        float4 f0 = b4f(wp[tid]);
        float4 f1 = b4f(wp[256 + tid]);
        float4 f2 = b4f(wp[512 + tid]);
        float4 f3 = b4f(wp[768 + tid]);
#pragma unroll
        for (int r = 0; r < 16; r++) {
            float4 xv = *(const float4*)&xsh[r][k4 << 2];
            acc[r][0] += xv.x * f0.x + xv.y * f0.y + xv.z * f0.z + xv.w * f0.w;
            acc[r][1] += xv.x * f1.x + xv.y * f1.y + xv.z * f1.z + xv.w * f1.w;
            acc[r][2] += xv.x * f2.x + xv.y * f2.y + xv.z * f2.z + xv.w * f2.w;
            acc[r][3] += xv.x * f3.x + xv.y * f3.y + xv.z * f3.z + xv.w * f3.w;
        }
    }
#pragma unroll
    for (int r = 0; r < 16; r++) {
        size_t base = (r0 + r) * GG;
#pragma unroll
        for (int q = 0; q < 4; q++)
            xw[base + (q << 8) + tid] = __float2bfloat16(acc[r][q]);
    }
}

// ---------------- LSTM scan: 2 batches/block, sync-free across blocks ----------------
__global__ __launch_bounds__(256) void lstm_kernel(
    const ushort4* __restrict__ Whh4, const ushort4* __restrict__ Wih4,
    const __hip_bfloat16* __restrict__ xw, const float* __restrict__ x,
    const float* __restrict__ b_ih, const float* __restrict__ b_hh,
    const int* __restrict__ lengths, float* __restrict__ pooled, int use_xw)
{
    __shared__ __align__(16) float hsh[2][HH];
    __shared__ __align__(16) float xsh[2][INP];
    int tid = threadIdx.x;
    int b0 = blockIdx.x << 1;
    hsh[0][tid] = 0.f; hsh[1][tid] = 0.f;
    float c0 = 0.f, c1 = 0.f, pa0 = 0.f, pa1 = 0.f;
    int len0 = lengths[b0], len1 = lengths[b0 + 1];
    float bsum[4];
#pragma unroll
    for (int q = 0; q < 4; q++) bsum[q] = b_ih[(q << 8) + tid] + b_hh[(q << 8) + tid];
    __syncthreads();

    for (int t = 0; t < SS; t++) {
        float a00, a01, a02, a03, a10, a11, a12, a13;
        if (use_xw) {
            const __hip_bfloat16* p0 = xw + ((size_t)b0 * SS + t) * GG;
            const __hip_bfloat16* p1 = xw + ((size_t)(b0 + 1) * SS + t) * GG;
            a00 = __bfloat162float(p0[tid]);       a01 = __bfloat162float(p0[256 + tid]);
            a02 = __bfloat162float(p0[512 + tid]); a03 = __bfloat162float(p0[768 + tid]);
            a10 = __bfloat162float(p1[tid]);       a11 = __bfloat162float(p1[256 + tid]);
            a12 = __bfloat162float(p1[512 + tid]); a13 = __bfloat162float(p1[768 + tid]);
        } else {
            a00 = bsum[0]; a01 = bsum[1]; a02 = bsum[2]; a03 = bsum[3];
            a10 = bsum[0]; a11 = bsum[1]; a12 = bsum[2]; a13 = bsum[3];
            for (int i = tid; i < 2 * INP; i += 256) {
                int rr = i / INP, cc = i % INP;
                xsh[rr][cc] = (cc < INW) ? x[((size_t)(b0 + rr) * SS + t) * INW + cc] : 0.f;
            }
            __syncthreads();
            for (int k4 = 0; k4 < 33; k4++) {
                const ushort4* wp = Wih4 + (k4 << 10);
                float4 f0 = b4f(wp[tid]), f1 = b4f(wp[256 + tid]);
                float4 f2 = b4f(wp[512 + tid]), f3 = b4f(wp[768 + tid]);
                float4 ha = *(const float4*)&xsh[0][k4 << 2];
                float4 hb = *(const float4*)&xsh[1][k4 << 2];
                a00 += ha.x * f0.x + ha.y * f0.y + ha.z * f0.z + ha.w * f0.w;
                a01 += ha.x * f1.x + ha.y * f1.y + ha.z * f1.z + ha.w * f1.w;
                a02 += ha.x * f2.x + ha.y * f2.y + ha.z * f2.z + ha.w * f2.w;
                a03 += ha.x * f3.x + ha.y * f3.y + ha.z * f3.z + ha.w * f3.w;
                a10 += hb.x * f0.x + hb.y * f0.y + hb.z * f0.z + hb.w * f0.w;
                a11 += hb.x * f1.x + hb.y * f1.y + hb.z * f1.z + hb.w * f1.w;
                a12 += hb.x * f2.x + hb.y * f2.y + hb.z * f2.z + hb.w * f2.w;
                a13 += hb.x * f3.x + hb.y * f3.y + hb.z * f3.z + hb.w * f3.w;
            }
        }
#pragma unroll 4
        for (int k4 = 0; k4 < 64; k4++) {
            const ushort4* wp = Whh4 + (k4 << 10);
            float4 f0 = b4f(wp[tid]), f1 = b4f(wp[256 + tid]);
            float4 f2 = b4f(wp[512 + tid]), f3 = b4f(wp[768 + tid]);
            float4 ha = *(const float4*)&hsh[0][k4 << 2];
            float4 hb = *(const float4*)&hsh[1][k4 << 2];
            a00 += ha.x * f0.x + ha.y * f0.y + ha.z * f0.z + ha.w * f0.w;
            a01 += ha.x * f1.x + ha.y * f1.y + ha.z * f1.z + ha.w * f1.w;
            a02 += ha.x * f2.x + ha.y * f2.y + ha.z * f2.z + ha.w * f2.w;
            a03 += ha.x * f3.x + ha.y * f3.y + ha.z * f3.z + ha.w * f3.w;
            a10 += hb.x * f0.x + hb.y * f0.y + hb.z * f0.z + hb.w * f0.w;
            a11 += hb.x * f1.x + hb.y * f1.y + hb.z * f1.z + hb.w * f1.w;
            a12 += hb.x * f2.x + hb.y * f2.y + hb.z * f2.z + hb.w * f2.w;
            a13 += hb.x * f3.x + hb.y * f3.y + hb.z * f3.z + hb.w * f3.w;
        }
        float h0, h1;
        {
            float ig = sigf(a00), fg = sigf(a01), gg = tanhf_(a02), og = sigf(a03);
            c0 = fg * c0 + ig * gg; h0 = og * tanhf_(c0);
        }
        {
            float ig = sigf(a10), fg = sigf(a11), gg = tanhf_(a12), og = sigf(a13);
            c1 = fg * c1 + ig * gg; h1 = og * tanhf_(c1);
        }
        if (t < len0) pa0 += h0;
        if (t < len1) pa1 += h1;
        __syncthreads();
        hsh[0][tid] = h0; hsh[1][tid] = h1;
        __syncthreads();
    }
    pooled[(size_t)b0 * HH + tid] = pa0 / (float)len0;
    pooled[(size_t)(b0 + 1) * HH + tid] = pa1 / (float)len1;
}

// ---------------- head: y0 = relu(pooled@Wp1^T+bp1)@Wp2^T + bp2 ----------------
__global__ __launch_bounds__(256) void head_kernel(
    const float* __restrict__ pooled, const float* __restrict__ Wp1,
    const float* __restrict__ bp1, const float* __restrict__ Wp2,
    const float* __restrict__ bp2, float* __restrict__ y0ws)
{
    __shared__ __align__(16) float psh[HH];
    __shared__ __align__(16) float rsh[HH];
    int tid = threadIdx.x, b = blockIdx.x;
    psh[tid] = pooled[(size_t)b * HH + tid];
    __syncthreads();
    float a = bp1[tid];
    const float* wr = Wp1 + (size_t)tid * HH;
#pragma unroll 8
    for (int k = 0; k < HH; k += 4) {
        float4 w = *(const float4*)(wr + k);
        a += psh[k] * w.x + psh[k + 1] * w.y + psh[k + 2] * w.z + psh[k + 3] * w.w;
    }
    rsh[tid] = fmaxf(a, 0.f);
    __syncthreads();
    if (tid < DD) {
        float acc = bp2[tid];
        const float* w2 = Wp2 + (size_t)tid * HH;
#pragma unroll 8
        for (int h = 0; h < HH; h += 4) {
            float4 w = *(const float4*)(w2 + h);
            acc += rsh[h] * w.x + rsh[h + 1] * w.y + rsh[h + 2] * w.z + rsh[h + 3] * w.w;
        }
        y0ws[(size_t)b * DD + tid] = acc;
    }
}

// ---------------- ODE: RK4, 1 batch/block, weights in registers ----------------
__global__ __launch_bounds__(256) void ode_kernel(
    const float* __restrict__ y0ws, const float* __restrict__ Wd1,
    const float* __restrict__ bd1, const float* __restrict__ Wd2,
    const float* __restrict__ bd2, const float* __restrict__ ltime,
    const float* __restrict__ lfeat, const float* __restrict__ lmask,
    float* __restrict__ pred, float* __restrict__ losso)
{
    __shared__ __align__(16) float ysh[DD];
    __shared__ __align__(16) float hshs[HH];
    int tid = threadIdx.x;
    int w = tid >> 6, l = tid & 63;
    int o = (w << 4) + (l & 15), q = l >> 4;   // o in [0,64), q in [0,4)
    int b = blockIdx.x;
    float4 w1[16], w2[16];
#pragma unroll
    for (int c = 0; c < 16; c++) w1[c] = *(const float4*)(Wd1 + (size_t)tid * DD + (c << 2));
#pragma unroll
    for (int c = 0; c < 16; c++) w2[c] = *(const float4*)(Wd2 + (size_t)o * HH + (q << 6) + (c << 2));
    float bd1t = bd1[tid];
    float bd2o = bd2[o];
    float y = y0ws[(size_t)b * DD + o];
    if (q == 0) {
        size_t idx = ((size_t)b * TT + 0) * DD + o;
        pred[idx] = y;
        float lf = lfeat[idx], lm = lmask[idx];
        losso[idx] = (y - lf) * (y - lf) * (1.f - lm);
    }
    float kp = 0.f;
    for (int iv = 0; iv < TT - 1; iv++) {
        float t0 = ltime[(size_t)b * TT + iv], t1 = ltime[(size_t)b * TT + iv + 1];
        float dt = (t1 - t0) * 0.125f;
        for (int ss = 0; ss < 8; ss++) {
            float sacc = 0.f;
            kp = 0.f;
            const float AE[4] = {0.f, 0.5f, 0.5f, 1.f};
            const float WE[4] = {1.f, 2.f, 2.f, 1.f};
#pragma unroll
            for (int e = 0; e < 4; e++) {
                if (q == 0) ysh[o] = y + AE[e] * dt * kp;
                __syncthreads();
                float hv = bd1t;
#pragma unroll
                for (int c = 0; c < 16; c++) {
                    float4 ww = w1[c];
                    float4 yv = *(const float4*)&ysh[c << 2];
                    hv += yv.x * ww.x + yv.y * ww.y + yv.z * ww.z + yv.w * ww.w;
                }
                hshs[tid] = fmaxf(hv, 0.f);
                __syncthreads();
                float p = 0.f;
#pragma unroll
                for (int c = 0; c < 16; c++) {
                    float4 ww = w2[c];
                    float4 h4 = *(const float4*)&hshs[(q << 6) + (c << 2)];
                    p += h4.x * ww.x + h4.y * ww.y + h4.z * ww.z + h4.w * ww.w;
                }
                p += __shfl_xor(p, 16);
                p += __shfl_xor(p, 32);
                float kv = p + bd2o;
                kp = kv;
                sacc += WE[e] * kv;
            }
            y += dt * (1.f / 6.f) * sacc;
        }
        if (q == 0) {
            size_t idx = ((size_t)b * TT + iv + 1) * DD + o;
            pred[idx] = y;
            float lf = lfeat[idx], lm = lmask[idx];
            losso[idx] = (y - lf) * (y - lf) * (1.f - lm);
        }
    }
}

extern "C" void kernel_launch(void* const* d_in, const int* in_sizes, int n_in,
                              void* d_out, int out_size, void* d_ws, size_t ws_size,
                              hipStream_t stream)
{
    const float* x      = (const float*)d_in[0];
    const int* lengths  = (const int*)d_in[1];
    const float* lfeat  = (const float*)d_in[2];
    const float* ltime  = (const float*)d_in[3];
    const float* lmask  = (const float*)d_in[4];
    const float* W_ih   = (const float*)d_in[5];
    const float* W_hh   = (const float*)d_in[6];
    const float* b_ih   = (const float*)d_in[7];
    const float* b_hh   = (const float*)d_in[8];
    const float* Wp1    = (const float*)d_in[9];
    const float* bp1    = (const float*)d_in[10];
    const float* Wp2    = (const float*)d_in[11];
    const float* bp2    = (const float*)d_in[12];
    const float* Wd1    = (const float*)d_in[13];
    const float* bd1    = (const float*)d_in[14];
    const float* Wd2    = (const float*)d_in[15];
    const float* bd2    = (const float*)d_in[16];

    float* pred  = (float*)d_out;
    float* losso = pred + (size_t)BB * TT * DD;

    char* ws = (char*)d_ws;
    ushort4* Whh4 = (ushort4*)(ws + 0);                 //   524288 B
    ushort4* Wih4 = (ushort4*)(ws + 524288);            //   270336 B
    float* pooled = (float*)(ws + 794624);              //   524288 B
    float* y0ws   = (float*)(ws + 1318912);             //   131072 B
    __hip_bfloat16* xw = (__hip_bfloat16*)(ws + 1449984);  // 268435456 B
    const size_t NEED_FULL = 1449984ull + (size_t)BB * SS * GG * 2ull;
    int use_xw = (ws_size >= NEED_FULL) ? 1 : 0;

    prep_kernel<<<388, 256, 0, stream>>>(W_hh, W_ih, Whh4, Wih4);
    if (use_xw)
        xw_kernel<<<(BB * SS) / 16, 256, 0, stream>>>(x, Wih4, b_ih, b_hh, xw);
    lstm_kernel<<<BB / 2, 256, 0, stream>>>(Whh4, Wih4, xw, x, b_ih, b_hh, lengths, pooled, use_xw);
    head_kernel<<<BB, 256, 0, stream>>>(pooled, Wp1, bp1, Wp2, bp2, y0ws);
    ode_kernel<<<BB, 256, 0, stream>>>(y0ws, Wd1, bd1, Wd2, bd2, ltime, lfeat, lmask, pred, losso);
}

// Round 3
// 4242.925 us; speedup vs baseline: 1.0759x; 1.0759x over previous
//
#include <hip/hip_runtime.h>
#include <hip/hip_bf16.h>

#define BB 512
#define SS 256
#define HH 256
#define DD 64
#define TT 50
#define GG 1024   // 4*H
#define INW 129

typedef _Float16 h4 __attribute__((ext_vector_type(4)));
typedef _Float16 h8 __attribute__((ext_vector_type(8)));
typedef float f32x4 __attribute__((ext_vector_type(4)));

__device__ inline float sigf(float x) { return 1.f / (1.f + __expf(-x)); }
__device__ inline float tanhf_(float x) { return 1.f - 2.f / (__expf(2.f * x) + 1.f); }

// ============ prep: pack W_hh and W_ih into MFMA B-fragment layout (f16) ============
// Bhh[w][nt][ks][l][e] = W_hh[n][k], n = nt*256 + w*16 + (l&15), k = 32*ks + 8*(l>>4) + e
// Bih[ntile][ks][l][e] = W_ih[n][k] (0 if k>=129), n = ntile*16 + (l&15), k = 32*ks + 8*(l>>4) + e
__global__ __launch_bounds__(256) void prep_kernel(
    const float* __restrict__ W_hh, const float* __restrict__ W_ih,
    _Float16* __restrict__ Bhh, _Float16* __restrict__ Bih)
{
    int idx = blockIdx.x * 256 + threadIdx.x;
    if (idx < 65536) {
        int eh = idx & 1;
        int l = (idx >> 1) & 63;
        int slot = idx >> 7;           // [0,512) = (w*4+nt)*8 + ks
        int ks = slot & 7;
        int wnt = slot >> 3;           // [0,64) = w*4+nt
        int w = wnt >> 2, nt = wnt & 3;
        int n = nt * 256 + w * 16 + (l & 15);
        int k = 32 * ks + 8 * (l >> 4) + 4 * eh;
        float4 v = *(const float4*)(W_hh + (size_t)n * HH + k);
        h4 o; o[0] = (_Float16)v.x; o[1] = (_Float16)v.y; o[2] = (_Float16)v.z; o[3] = (_Float16)v.w;
        *(h4*)(Bhh + (size_t)idx * 4) = o;
    } else if (idx < 65536 + 40960) {
        int fj = idx - 65536;
        int eh = fj & 1;
        int l = (fj >> 1) & 63;
        int si = fj >> 7;              // [0,320) = ntile*5 + ks
        int ks = si % 5;
        int ntile = si / 5;
        int n = ntile * 16 + (l & 15);
        int k = 32 * ks + 8 * (l >> 4) + 4 * eh;
        h4 o;
#pragma unroll
        for (int i = 0; i < 4; i++) {
            int kk = k + i;
            o[i] = (_Float16)((kk < INW) ? W_ih[(size_t)n * INW + kk] : 0.f);
        }
        *(h4*)(Bih + (size_t)fj * 4) = o;
    }
}

// ============ xw GEMM (MFMA): gates pre-activation, written in C-frag layout ============
__global__ __launch_bounds__(256) void xw_kernel(
    const float* __restrict__ x, const _Float16* __restrict__ Bih,
    const float* __restrict__ b_ih, const float* __restrict__ b_hh,
    h4* __restrict__ xwf)
{
    __shared__ __align__(16) _Float16 ash[4][5][64][8];   // 20 KB, A-frag layout
    int tid = threadIdx.x;
    int w4 = tid >> 6, l = tid & 63;
    int bx = blockIdx.x;
    int t = bx >> 3, Bb = bx & 7;           // 64 batch-rows: b = Bb*64 + rr

    // stage x -> LDS (f32 -> f16, A-fragment layout), K padded to 160.
    // COVER THE FULL PAD [0,160): k in [129,160) must be written with 0 —
    // stale LDS garbage here can be NaN/Inf and NaN*0 = NaN in the MFMA.
    for (int i = tid; i < 64 * 160; i += 256) {
        int rr = i / 160, kk = i % 160;
        float v = (kk < INW) ? x[((size_t)(Bb * 64 + rr) * SS + t) * INW + kk] : 0.f;
        ash[rr >> 4][kk >> 5][(((kk & 31) >> 3) << 4) + (rr & 15)][kk & 7] = (_Float16)v;
    }
    __syncthreads();

    h8 A[4][5];
#pragma unroll
    for (int ms = 0; ms < 4; ms++)
#pragma unroll
        for (int ks = 0; ks < 5; ks++)
            A[ms][ks] = *(h8*)&ash[ms][ks][l][0];

    const h8* Bih8 = (const h8*)Bih;
    for (int nt16 = 0; nt16 < 16; nt16++) {
        int ntile = w4 * 16 + nt16;
        h8 Bv[5];
#pragma unroll
        for (int ks = 0; ks < 5; ks++) Bv[ks] = Bih8[(ntile * 5 + ks) * 64 + l];
        int nb = ntile * 16 + (l & 15);
        float bias = b_ih[nb] + b_hh[nb];
        f32x4 acc[4];
#pragma unroll
        for (int ms = 0; ms < 4; ms++) acc[ms] = (f32x4){0.f, 0.f, 0.f, 0.f};
#pragma unroll
        for (int ks = 0; ks < 5; ks++)
#pragma unroll
            for (int ms = 0; ms < 4; ms++)
                acc[ms] = __builtin_amdgcn_mfma_f32_16x16x32_f16(A[ms][ks], Bv[ks], acc[ms], 0, 0, 0);
        int slot = (ntile & 15) * 4 + (ntile >> 4);
#pragma unroll
        for (int ms = 0; ms < 4; ms++) {
            int bg = Bb * 4 + ms;
            h4 o;
#pragma unroll
            for (int r = 0; r < 4; r++) o[r] = (_Float16)(acc[ms][r] + bias);
            xwf[(((size_t)bg * SS + t) * 64 + slot) * 64 + l] = o;
        }
    }
}

// ============ LSTM: 32 blocks x 1024 thr; 16 batches/block; W_hh resident in VGPRs ============
__global__ __launch_bounds__(1024, 4) void lstm_kernel(
    const _Float16* __restrict__ Bhh, const h4* __restrict__ xwf,
    const int* __restrict__ lengths, float* __restrict__ pooled)
{
    __shared__ __align__(16) _Float16 hbuf[2][8][64][8];  // 16 KB double-buffered A-frag h
    int tid = threadIdx.x;
    int w = tid >> 6, l = tid & 63;
    int bg = blockIdx.x;
    int jcol = w * 16 + (l & 15);           // h index this lane's C-cols correspond to

    const h8* Bhh8 = (const h8*)Bhh;
    h8 Wf[4][8];
#pragma unroll
    for (int nt = 0; nt < 4; nt++)
#pragma unroll
        for (int ks = 0; ks < 8; ks++)
            Wf[nt][ks] = Bhh8[((w * 4 + nt) * 8 + ks) * 64 + l];

    int len_[4];
    float c_[4], pa[4];
#pragma unroll
    for (int r = 0; r < 4; r++) {
        int b = 4 * (l >> 4) + r;
        len_[r] = lengths[bg * 16 + b];
        c_[r] = 0.f; pa[r] = 0.f;
    }

    // zero h buffers (h0 = 0): 1024 uint4 = 16 KB, exactly one per thread
    ((uint4*)hbuf)[tid] = make_uint4(0, 0, 0, 0);
    __syncthreads();

    int cur = 0;
    for (int t = 0; t < SS; t++) {
        const h4* xp = xwf + (((size_t)bg * SS + t) * 64 + w * 4) * 64 + l;
        h4 xv[4];
        xv[0] = xp[0]; xv[1] = xp[64]; xv[2] = xp[128]; xv[3] = xp[192];

        h8 A[8];
#pragma unroll
        for (int ks = 0; ks < 8; ks++) A[ks] = *(h8*)&hbuf[cur][ks][l][0];

        f32x4 acc[4];
#pragma unroll
        for (int nt = 0; nt < 4; nt++) acc[nt] = (f32x4){0.f, 0.f, 0.f, 0.f};
#pragma unroll
        for (int ks = 0; ks < 8; ks++)
#pragma unroll
            for (int nt = 0; nt < 4; nt++)
                acc[nt] = __builtin_amdgcn_mfma_f32_16x16x32_f16(A[ks], Wf[nt][ks], acc[nt], 0, 0, 0);

#pragma unroll
        for (int r = 0; r < 4; r++) {
            float gi = acc[0][r] + (float)xv[0][r];
            float gf = acc[1][r] + (float)xv[1][r];
            float gg = acc[2][r] + (float)xv[2][r];
            float go = acc[3][r] + (float)xv[3][r];
            c_[r] = sigf(gf) * c_[r] + sigf(gi) * tanhf_(gg);
            float h = sigf(go) * tanhf_(c_[r]);
            if (t < len_[r]) pa[r] += h;
            int b = 4 * (l >> 4) + r;
            hbuf[cur ^ 1][jcol >> 5][(((jcol & 31) >> 3) << 4) + b][jcol & 7] = (_Float16)h;
        }
        __syncthreads();
        cur ^= 1;
    }

#pragma unroll
    for (int r = 0; r < 4; r++) {
        int b = 4 * (l >> 4) + r;
        pooled[(size_t)(bg * 16 + b) * HH + jcol] = pa[r] / (float)len_[r];
    }
}

// ============ head: y0 = relu(pooled@Wp1^T+bp1)@Wp2^T + bp2 ============
__global__ __launch_bounds__(256) void head_kernel(
    const float* __restrict__ pooled, const float* __restrict__ Wp1,
    const float* __restrict__ bp1, const float* __restrict__ Wp2,
    const float* __restrict__ bp2, float* __restrict__ y0ws)
{
    __shared__ __align__(16) float psh[HH];
    __shared__ __align__(16) float rsh[HH];
    int tid = threadIdx.x, b = blockIdx.x;
    psh[tid] = pooled[(size_t)b * HH + tid];
    __syncthreads();
    float a = bp1[tid];
    const float* wr = Wp1 + (size_t)tid * HH;
#pragma unroll 8
    for (int k = 0; k < HH; k += 4) {
        float4 w = *(const float4*)(wr + k);
        a += psh[k] * w.x + psh[k + 1] * w.y + psh[k + 2] * w.z + psh[k + 3] * w.w;
    }
    rsh[tid] = fmaxf(a, 0.f);
    __syncthreads();
    if (tid < DD) {
        float acc = bp2[tid];
        const float* w2 = Wp2 + (size_t)tid * HH;
#pragma unroll 8
        for (int h = 0; h < HH; h += 4) {
            float4 w = *(const float4*)(w2 + h);
            acc += rsh[h] * w.x + rsh[h + 1] * w.y + rsh[h + 2] * w.z + rsh[h + 3] * w.w;
        }
        y0ws[(size_t)b * DD + tid] = acc;
    }
}

// ============ ODE: RK4, 1 batch/block, weights in registers ============
__global__ __launch_bounds__(256) void ode_kernel(
    const float* __restrict__ y0ws, const float* __restrict__ Wd1,
    const float* __restrict__ bd1, const float* __restrict__ Wd2,
    const float* __restrict__ bd2, const float* __restrict__ ltime,
    const float* __restrict__ lfeat, const float* __restrict__ lmask,
    float* __restrict__ pred, float* __restrict__ losso)
{
    __shared__ __align__(16) float ysh[DD];
    __shared__ __align__(16) float hshs[HH];
    int tid = threadIdx.x;
    int wv = tid >> 6, lq = tid & 63;
    int o = (wv << 4) + (lq & 15), q = lq >> 4;   // o in [0,64), q in [0,4)
    int b = blockIdx.x;
    float4 w1[16], w2[16];
#pragma unroll
    for (int c = 0; c < 16; c++) w1[c] = *(const float4*)(Wd1 + (size_t)tid * DD + (c << 2));
#pragma unroll
    for (int c = 0; c < 16; c++) w2[c] = *(const float4*)(Wd2 + (size_t)o * HH + (q << 6) + (c << 2));
    float bd1t = bd1[tid];
    float bd2o = bd2[o];
    float y = y0ws[(size_t)b * DD + o];
    if (q == 0) {
        size_t idx = ((size_t)b * TT + 0) * DD + o;
        pred[idx] = y;
        float lf = lfeat[idx], lm = lmask[idx];
        losso[idx] = (y - lf) * (y - lf) * (1.f - lm);
    }
    float kp = 0.f;
    for (int iv = 0; iv < TT - 1; iv++) {
        float t0 = ltime[(size_t)b * TT + iv], t1 = ltime[(size_t)b * TT + iv + 1];
        float dt = (t1 - t0) * 0.125f;
        for (int ss = 0; ss < 8; ss++) {
            float sacc = 0.f;
            kp = 0.f;
            const float AE[4] = {0.f, 0.5f, 0.5f, 1.f};
            const float WE[4] = {1.f, 2.f, 2.f, 1.f};
#pragma unroll
            for (int e = 0; e < 4; e++) {
                if (q == 0) ysh[o] = y + AE[e] * dt * kp;
                __syncthreads();
                float hv = bd1t;
#pragma unroll
                for (int c = 0; c < 16; c++) {
                    float4 ww = w1[c];
                    float4 yv = *(const float4*)&ysh[c << 2];
                    hv += yv.x * ww.x + yv.y * ww.y + yv.z * ww.z + yv.w * ww.w;
                }
                hshs[tid] = fmaxf(hv, 0.f);
                __syncthreads();
                float p = 0.f;
#pragma unroll
                for (int c = 0; c < 16; c++) {
                    float4 ww = w2[c];
                    float4 hh = *(const float4*)&hshs[(q << 6) + (c << 2)];
                    p += hh.x * ww.x + hh.y * ww.y + hh.z * ww.z + hh.w * ww.w;
                }
                p += __shfl_xor(p, 16);
                p += __shfl_xor(p, 32);
                float kv = p + bd2o;
                kp = kv;
                sacc += WE[e] * kv;
            }
            y += dt * (1.f / 6.f) * sacc;
        }
        if (q == 0) {
            size_t idx = ((size_t)b * TT + iv + 1) * DD + o;
            pred[idx] = y;
            float lf = lfeat[idx], lm = lmask[idx];
            losso[idx] = (y - lf) * (y - lf) * (1.f - lm);
        }
    }
}

extern "C" void kernel_launch(void* const* d_in, const int* in_sizes, int n_in,
                              void* d_out, int out_size, void* d_ws, size_t ws_size,
                              hipStream_t stream)
{
    const float* x      = (const float*)d_in[0];
    const int* lengths  = (const int*)d_in[1];
    const float* lfeat  = (const float*)d_in[2];
    const float* ltime  = (const float*)d_in[3];
    const float* lmask  = (const float*)d_in[4];
    const float* W_ih   = (const float*)d_in[5];
    const float* W_hh   = (const float*)d_in[6];
    const float* b_ih   = (const float*)d_in[7];
    const float* b_hh   = (const float*)d_in[8];
    const float* Wp1    = (const float*)d_in[9];
    const float* bp1    = (const float*)d_in[10];
    const float* Wp2    = (const float*)d_in[11];
    const float* bp2    = (const float*)d_in[12];
    const float* Wd1    = (const float*)d_in[13];
    const float* bd1    = (const float*)d_in[14];
    const float* Wd2    = (const float*)d_in[15];
    const float* bd2    = (const float*)d_in[16];

    float* pred  = (float*)d_out;
    float* losso = pred + (size_t)BB * TT * DD;

    char* ws = (char*)d_ws;
    h4*       xwf    = (h4*)(ws + 0);                         // 268435456 B
    _Float16* Bhh    = (_Float16*)(ws + 268435456);           //    524288 B
    _Float16* Bih    = (_Float16*)(ws + 268959744);           //    327680 B
    float*    pooled = (float*)(ws + 269287424);              //    524288 B
    float*    y0ws   = (float*)(ws + 269811712);              //    131072 B

    prep_kernel<<<416, 256, 0, stream>>>(W_hh, W_ih, Bhh, Bih);
    xw_kernel<<<2048, 256, 0, stream>>>(x, Bih, b_ih, b_hh, xwf);
    lstm_kernel<<<32, 1024, 0, stream>>>(Bhh, xwf, lengths, pooled);
    head_kernel<<<BB, 256, 0, stream>>>(pooled, Wp1, bp1, Wp2, bp2, y0ws);
    ode_kernel<<<BB, 256, 0, stream>>>(y0ws, Wd1, bd1, Wd2, bd2, ltime, lfeat, lmask, pred, losso);
}

// Round 5
// 2271.456 us; speedup vs baseline: 2.0096x; 1.8679x over previous
//
#include <hip/hip_runtime.h>
#include <hip/hip_bf16.h>

#define BB 512
#define SS 256
#define HH 256
#define DD 64
#define TT 50
#define GG 1024   // 4*H
#define INW 129

typedef _Float16 h4 __attribute__((ext_vector_type(4)));
typedef _Float16 h8 __attribute__((ext_vector_type(8)));
typedef __fp16 hf2 __attribute__((ext_vector_type(2)));   // builtin-facing f16 pair
typedef float f32x4 __attribute__((ext_vector_type(4)));
typedef unsigned int u32;

__device__ inline float sigf(float x) { return 1.f / (1.f + __expf(-x)); }
__device__ inline float tanhf_(float x) { return 1.f - 2.f / (__expf(2.f * x) + 1.f); }

__device__ inline u32 pkrtz(float a, float b) {
    hf2 h = __builtin_amdgcn_cvt_pkrtz(a, b);
    return __builtin_bit_cast(u32, h);
}
__device__ inline float fdot2u(u32 a, u32 b, float c) {
    return __builtin_amdgcn_fdot2(__builtin_bit_cast(hf2, a), __builtin_bit_cast(hf2, b), c, false);
}

// ============ prep ============
// W_hh B-fragments for the 8-wave LSTM. Wave w (of 8), slot s = jt*4+g (g=gate, jt=j-subtile):
//   value(l,e) = W_hh[n][k], n = g*256 + w*32 + jt*16 + (l&15), k = 32ks + 8*(l>>4) + e
//   ks 0-3 -> BhhV (VGPR-resident), ks 4-5 -> BhhL (LDS image), ks 6-7 -> BhhS (L2-streamed)
// Bih unchanged from validated round-3 layout.
// Wd1p[j*256+i]  = pack_f16(Wd1[i][2j],  Wd1[i][2j+1])          (j<32, i<256)
// Wd2p[j*256+t]  = pack_f16(Wd2[o][64q+2j], Wd2[o][64q+2j+1]),  o=((t>>6)<<4)+(t&15), q=(t>>4)&3
__global__ __launch_bounds__(256) void prep_kernel(
    const float* __restrict__ W_hh, const float* __restrict__ W_ih,
    const float* __restrict__ Wd1, const float* __restrict__ Wd2,
    h4* __restrict__ BhhV4, h4* __restrict__ BhhL4, h4* __restrict__ BhhS4,
    _Float16* __restrict__ Bih, u32* __restrict__ Wd1p, u32* __restrict__ Wd2p)
{
    int idx = blockIdx.x * 256 + threadIdx.x;
    if (idx < 65536) {
        int eh = idx & 1;
        int l = (idx >> 1) & 63;
        int ks = (idx >> 7) & 7;
        int s = (idx >> 10) & 7;
        int w = (idx >> 13) & 7;
        int g = s & 3, jt = s >> 2;
        int n = g * 256 + w * 32 + jt * 16 + (l & 15);
        int k = 32 * ks + 8 * (l >> 4) + 4 * eh;
        float4 v = *(const float4*)(W_hh + (size_t)n * HH + k);
        h4 o; o[0] = (_Float16)v.x; o[1] = (_Float16)v.y; o[2] = (_Float16)v.z; o[3] = (_Float16)v.w;
        if (ks < 4)      BhhV4[(((w * 8 + s) * 4 + ks) * 64 + l) * 2 + eh] = o;
        else if (ks < 6) BhhL4[(((w * 8 + s) * 2 + (ks - 4)) * 64 + l) * 2 + eh] = o;
        else             BhhS4[(((w * 8 + s) * 2 + (ks - 6)) * 64 + l) * 2 + eh] = o;
    } else if (idx < 65536 + 40960) {
        int fj = idx - 65536;
        int eh = fj & 1;
        int l = (fj >> 1) & 63;
        int si = fj >> 7;              // [0,320) = ntile*5 + ks
        int ks = si % 5;
        int ntile = si / 5;
        int n = ntile * 16 + (l & 15);
        int k = 32 * ks + 8 * (l >> 4) + 4 * eh;
        h4 o;
#pragma unroll
        for (int i = 0; i < 4; i++) {
            int kk = k + i;
            o[i] = (_Float16)((kk < INW) ? W_ih[(size_t)n * INW + kk] : 0.f);
        }
        *(h4*)(Bih + (size_t)fj * 4) = o;
    } else if (idx < 106496 + 8192) {
        int j2 = idx - 106496;
        int j = j2 >> 8, i = j2 & 255;
        Wd1p[j2] = pkrtz(Wd1[i * DD + 2 * j], Wd1[i * DD + 2 * j + 1]);
    } else if (idx < 114688 + 8192) {
        int j2 = idx - 114688;
        int j = j2 >> 8, t = j2 & 255;
        int o = ((t >> 6) << 4) + (t & 15);
        int q = (t >> 4) & 3;
        Wd2p[j2] = pkrtz(Wd2[(size_t)o * HH + q * 64 + 2 * j],
                         Wd2[(size_t)o * HH + q * 64 + 2 * j + 1]);
    }
}

// ============ xw GEMM (MFMA): validated round-3 kernel, slot remapped for 8-wave LSTM ============
__global__ __launch_bounds__(256) void xw_kernel(
    const float* __restrict__ x, const _Float16* __restrict__ Bih,
    const float* __restrict__ b_ih, const float* __restrict__ b_hh,
    h4* __restrict__ xwf)
{
    __shared__ __align__(16) _Float16 ash[4][5][64][8];   // 20 KB, A-frag layout
    int tid = threadIdx.x;
    int w4 = tid >> 6, l = tid & 63;
    int bx = blockIdx.x;
    int t = bx >> 3, Bb = bx & 7;           // 64 batch-rows: b = Bb*64 + rr

    // stage x -> LDS (f32 -> f16, A-frag layout); cover full K-pad [0,160) with zeros
    for (int i = tid; i < 64 * 160; i += 256) {
        int rr = i / 160, kk = i % 160;
        float v = (kk < INW) ? x[((size_t)(Bb * 64 + rr) * SS + t) * INW + kk] : 0.f;
        ash[rr >> 4][kk >> 5][(((kk & 31) >> 3) << 4) + (rr & 15)][kk & 7] = (_Float16)v;
    }
    __syncthreads();

    h8 A[4][5];
#pragma unroll
    for (int ms = 0; ms < 4; ms++)
#pragma unroll
        for (int ks = 0; ks < 5; ks++)
            A[ms][ks] = *(h8*)&ash[ms][ks][l][0];

    const h8* Bih8 = (const h8*)Bih;
    for (int nt16 = 0; nt16 < 16; nt16++) {
        int ntile = w4 * 16 + nt16;
        h8 Bv[5];
#pragma unroll
        for (int ks = 0; ks < 5; ks++) Bv[ks] = Bih8[(ntile * 5 + ks) * 64 + l];
        int nb = ntile * 16 + (l & 15);
        float bias = b_ih[nb] + b_hh[nb];
        f32x4 acc[4];
#pragma unroll
        for (int ms = 0; ms < 4; ms++) acc[ms] = (f32x4){0.f, 0.f, 0.f, 0.f};
#pragma unroll
        for (int ks = 0; ks < 5; ks++)
#pragma unroll
            for (int ms = 0; ms < 4; ms++)
                acc[ms] = __builtin_amdgcn_mfma_f32_16x16x32_f16(A[ms][ks], Bv[ks], acc[ms], 0, 0, 0);
        // slot for 8-wave LSTM: w = (ntile&15)>>1, jt = ntile&1, g = ntile>>4
        int slot = ((ntile & 15) >> 1) * 8 + (ntile & 1) * 4 + (ntile >> 4);
#pragma unroll
        for (int ms = 0; ms < 4; ms++) {
            int bg = Bb * 4 + ms;
            h4 o;
#pragma unroll
            for (int r = 0; r < 4; r++) o[r] = (_Float16)(acc[ms][r] + bias);
            xwf[(((size_t)bg * SS + t) * 64 + slot) * 64 + l] = o;
        }
    }
}

// ============ LSTM v3: 32 blocks x 512 thr (8 waves, 2/SIMD, 256-VGPR budget) ============
// Wave w owns j-cols [32w, 32w+32) for all 4 gates. Weights: ks0-3 VGPR, ks4-5 LDS, ks6-7 L2-stream.
__global__ __launch_bounds__(512, 2) void lstm_kernel(
    const h8* __restrict__ BhhV, const h8* __restrict__ BhhL, const h8* __restrict__ BhhS,
    const h4* __restrict__ xwf, const int* __restrict__ lengths, float* __restrict__ pooled)
{
    __shared__ __align__(16) _Float16 Wlds[65536];        // 128 KB: ks4-5 weight fragments
    __shared__ __align__(16) _Float16 hbuf[2][8][64][8];  // 16 KB double-buffered A-frag h
    int tid = threadIdx.x;
    int w = tid >> 6, l = tid & 63;
    int bg = blockIdx.x;

    // copy ks4-5 weights into LDS (linear, 128 KB)
    {
        const uint4* src = (const uint4*)BhhL;
        uint4* dst = (uint4*)Wlds;
#pragma unroll
        for (int i = 0; i < 16; i++) dst[i * 512 + tid] = src[i * 512 + tid];
    }

    // VGPR-resident weights: 8 slots x ks0-3 = 128 VGPRs
    h8 Wv[8][4];
#pragma unroll
    for (int s = 0; s < 8; s++)
#pragma unroll
        for (int ks = 0; ks < 4; ks++)
            Wv[s][ks] = BhhV[((w * 8 + s) * 4 + ks) * 64 + l];

    int len_[4];
    float c_[2][4], pa[2][4];
#pragma unroll
    for (int r = 0; r < 4; r++) {
        int b = 4 * (l >> 4) + r;
        len_[r] = lengths[bg * 16 + b];
#pragma unroll
        for (int jt = 0; jt < 2; jt++) { c_[jt][r] = 0.f; pa[jt][r] = 0.f; }
    }

    // zero h buffers (h0 = 0): 1024 uint4, 2 per thread
    {
        uint4* hz = (uint4*)hbuf;
        hz[tid] = make_uint4(0, 0, 0, 0);
        hz[512 + tid] = make_uint4(0, 0, 0, 0);
    }
    __syncthreads();

    int cur = 0;
    for (int t = 0; t < SS; t++) {
        const h4* xpb = xwf + (((size_t)bg * SS + t) * 64 + w * 8) * 64 + l;
        int zoff = 0;
        asm volatile("" : "+v"(zoff));            // block LICM: force per-step re-load of streamed weights
        const h8* bS = BhhS + zoff;
#pragma unroll
        for (int jt = 0; jt < 2; jt++) {
            h4 xv[4];
#pragma unroll
            for (int g = 0; g < 4; g++) xv[g] = xpb[(jt * 4 + g) * 64];
            h8 Ws[4];
#pragma unroll
            for (int g = 0; g < 4; g++) Ws[g] = bS[((w * 8 + jt * 4 + g) * 2 + 0) * 64 + l];
            f32x4 acc[4];
#pragma unroll
            for (int g = 0; g < 4; g++) acc[g] = (f32x4){0.f, 0.f, 0.f, 0.f};
            // ks 0-3 from VGPR
#pragma unroll
            for (int ks = 0; ks < 4; ks++) {
                h8 A = *(const h8*)&hbuf[cur][ks][l][0];
#pragma unroll
                for (int g = 0; g < 4; g++)
                    acc[g] = __builtin_amdgcn_mfma_f32_16x16x32_f16(A, Wv[jt * 4 + g][ks], acc[g], 0, 0, 0);
            }
            // ks 6 (streamed, landed)
            {
                h8 A = *(const h8*)&hbuf[cur][6][l][0];
#pragma unroll
                for (int g = 0; g < 4; g++)
                    acc[g] = __builtin_amdgcn_mfma_f32_16x16x32_f16(A, Ws[g], acc[g], 0, 0, 0);
            }
            // reissue stream for ks 7 into same regs
#pragma unroll
            for (int g = 0; g < 4; g++) Ws[g] = bS[((w * 8 + jt * 4 + g) * 2 + 1) * 64 + l];
            // ks 4-5 from LDS
#pragma unroll
            for (int ks = 4; ks < 6; ks++) {
                h8 A = *(const h8*)&hbuf[cur][ks][l][0];
#pragma unroll
                for (int g = 0; g < 4; g++) {
                    h8 Bw = *(const h8*)&Wlds[(((w * 8 + jt * 4 + g) * 2 + (ks - 4)) * 64 + l) * 8];
                    acc[g] = __builtin_amdgcn_mfma_f32_16x16x32_f16(A, Bw, acc[g], 0, 0, 0);
                }
            }
            // ks 7
            {
                h8 A = *(const h8*)&hbuf[cur][7][l][0];
#pragma unroll
                for (int g = 0; g < 4; g++)
                    acc[g] = __builtin_amdgcn_mfma_f32_16x16x32_f16(A, Ws[g], acc[g], 0, 0, 0);
            }
            // gates + h update
#pragma unroll
            for (int r = 0; r < 4; r++) {
                float gi = acc[0][r] + (float)xv[0][r];
                float gf = acc[1][r] + (float)xv[1][r];
                float gg = acc[2][r] + (float)xv[2][r];
                float go = acc[3][r] + (float)xv[3][r];
                float cc = sigf(gf) * c_[jt][r] + sigf(gi) * tanhf_(gg);
                c_[jt][r] = cc;
                float hh = sigf(go) * tanhf_(cc);
                if (t < len_[r]) pa[jt][r] += hh;
                int b = 4 * (l >> 4) + r;
                int j = w * 32 + jt * 16 + (l & 15);
                hbuf[cur ^ 1][j >> 5][(((j & 31) >> 3) << 4) + b][j & 7] = (_Float16)hh;
            }
        }
        __syncthreads();
        cur ^= 1;
    }

#pragma unroll
    for (int jt = 0; jt < 2; jt++)
#pragma unroll
        for (int r = 0; r < 4; r++) {
            int b = 4 * (l >> 4) + r;
            int j = w * 32 + jt * 16 + (l & 15);
            pooled[(size_t)(bg * 16 + b) * HH + j] = pa[jt][r] / (float)len_[r];
        }
}

// ============ head: y0 = relu(pooled@Wp1^T+bp1)@Wp2^T + bp2 ============
__global__ __launch_bounds__(256) void head_kernel(
    const float* __restrict__ pooled, const float* __restrict__ Wp1,
    const float* __restrict__ bp1, const float* __restrict__ Wp2,
    const float* __restrict__ bp2, float* __restrict__ y0ws)
{
    __shared__ __align__(16) float psh[HH];
    __shared__ __align__(16) float rsh[HH];
    int tid = threadIdx.x, b = blockIdx.x;
    psh[tid] = pooled[(size_t)b * HH + tid];
    __syncthreads();
    float a = bp1[tid];
    const float* wr = Wp1 + (size_t)tid * HH;
#pragma unroll 8
    for (int k = 0; k < HH; k += 4) {
        float4 w = *(const float4*)(wr + k);
        a += psh[k] * w.x + psh[k + 1] * w.y + psh[k + 2] * w.z + psh[k + 3] * w.w;
    }
    rsh[tid] = fmaxf(a, 0.f);
    __syncthreads();
    if (tid < DD) {
        float acc = bp2[tid];
        const float* w2 = Wp2 + (size_t)tid * HH;
#pragma unroll 8
        for (int h = 0; h < HH; h += 4) {
            float4 w = *(const float4*)(w2 + h);
            acc += rsh[h] * w.x + rsh[h + 1] * w.y + rsh[h + 2] * w.z + rsh[h + 3] * w.w;
        }
        y0ws[(size_t)b * DD + tid] = acc;
    }
}

// ============ ODE v2: RK4, 1 batch/block, packed-f16 weights + v_dot2_f32_f16 ============
__global__ __launch_bounds__(256) void ode_kernel(
    const float* __restrict__ y0ws, const u32* __restrict__ Wd1p,
    const float* __restrict__ bd1, const u32* __restrict__ Wd2p,
    const float* __restrict__ bd2, const float* __restrict__ ltime,
    const float* __restrict__ lfeat, const float* __restrict__ lmask,
    float* __restrict__ pred, float* __restrict__ losso)
{
    __shared__ __align__(16) u32 ysh16[32];    // packed f16 y pairs
    __shared__ __align__(16) u32 hsh16[128];   // packed f16 h pairs
    int tid = threadIdx.x;
    int wv = tid >> 6, lq = tid & 63;
    int o = (wv << 4) + (lq & 15), q = lq >> 4;
    int b = blockIdx.x;
    u32 w1p[32], w2p[32];
#pragma unroll
    for (int j = 0; j < 32; j++) w1p[j] = Wd1p[j * 256 + tid];
#pragma unroll
    for (int j = 0; j < 32; j++) w2p[j] = Wd2p[j * 256 + tid];
    float bd1t = bd1[tid];
    float bd2o = bd2[o];
    float y = y0ws[(size_t)b * DD + o];
    if (q == 0) {
        size_t idx = ((size_t)b * TT + 0) * DD + o;
        pred[idx] = y;
        float lf = lfeat[idx], lm = lmask[idx];
        losso[idx] = (y - lf) * (y - lf) * (1.f - lm);
    }
    float kp = 0.f;
    for (int iv = 0; iv < TT - 1; iv++) {
        float t0 = ltime[(size_t)b * TT + iv], t1 = ltime[(size_t)b * TT + iv + 1];
        float dt = (t1 - t0) * 0.125f;
        for (int ss = 0; ss < 8; ss++) {
            float sacc = 0.f;
            kp = 0.f;
            const float AE[4] = {0.f, 0.5f, 0.5f, 1.f};
            const float WE[4] = {1.f, 2.f, 2.f, 1.f};
#pragma unroll
            for (int e = 0; e < 4; e++) {
                float yp = y + AE[e] * dt * kp;         // all lanes (y, kp replicated per q)
                float ypo = __shfl_xor(yp, 1);
                if (lq < 16 && !(lq & 1))
                    ysh16[8 * wv + (lq >> 1)] = pkrtz(yp, ypo);
                __syncthreads();
                float a0 = 0.f, a1 = 0.f, a2 = 0.f, a3 = 0.f;
                const uint4* yv4 = (const uint4*)ysh16;
#pragma unroll
                for (int j4 = 0; j4 < 8; j4++) {
                    uint4 yv = yv4[j4];
                    a0 = fdot2u(w1p[4 * j4 + 0], yv.x, a0);
                    a1 = fdot2u(w1p[4 * j4 + 1], yv.y, a1);
                    a2 = fdot2u(w1p[4 * j4 + 2], yv.z, a2);
                    a3 = fdot2u(w1p[4 * j4 + 3], yv.w, a3);
                }
                float hv = fmaxf(bd1t + ((a0 + a1) + (a2 + a3)), 0.f);
                float hvo = __shfl_xor(hv, 1);
                if (!(tid & 1))
                    hsh16[tid >> 1] = pkrtz(hv, hvo);
                __syncthreads();
                float b0 = 0.f, b1 = 0.f, b2 = 0.f, b3 = 0.f;
                const uint4* hv4 = (const uint4*)&hsh16[q << 5];
#pragma unroll
                for (int j4 = 0; j4 < 8; j4++) {
                    uint4 hh = hv4[j4];
                    b0 = fdot2u(w2p[4 * j4 + 0], hh.x, b0);
                    b1 = fdot2u(w2p[4 * j4 + 1], hh.y, b1);
                    b2 = fdot2u(w2p[4 * j4 + 2], hh.z, b2);
                    b3 = fdot2u(w2p[4 * j4 + 3], hh.w, b3);
                }
                float p = (b0 + b1) + (b2 + b3);
                p += __shfl_xor(p, 16);
                p += __shfl_xor(p, 32);
                float kv = p + bd2o;
                kp = kv;
                sacc += WE[e] * kv;
            }
            y += dt * (1.f / 6.f) * sacc;
        }
        if (q == 0) {
            size_t idx = ((size_t)b * TT + iv + 1) * DD + o;
            pred[idx] = y;
            float lf = lfeat[idx], lm = lmask[idx];
            losso[idx] = (y - lf) * (y - lf) * (1.f - lm);
        }
    }
}

extern "C" void kernel_launch(void* const* d_in, const int* in_sizes, int n_in,
                              void* d_out, int out_size, void* d_ws, size_t ws_size,
                              hipStream_t stream)
{
    const float* x      = (const float*)d_in[0];
    const int* lengths  = (const int*)d_in[1];
    const float* lfeat  = (const float*)d_in[2];
    const float* ltime  = (const float*)d_in[3];
    const float* lmask  = (const float*)d_in[4];
    const float* W_ih   = (const float*)d_in[5];
    const float* W_hh   = (const float*)d_in[6];
    const float* b_ih   = (const float*)d_in[7];
    const float* b_hh   = (const float*)d_in[8];
    const float* Wp1    = (const float*)d_in[9];
    const float* bp1    = (const float*)d_in[10];
    const float* Wp2    = (const float*)d_in[11];
    const float* bp2    = (const float*)d_in[12];
    const float* Wd1    = (const float*)d_in[13];
    const float* bd1    = (const float*)d_in[14];
    const float* Wd2    = (const float*)d_in[15];
    const float* bd2    = (const float*)d_in[16];

    float* pred  = (float*)d_out;
    float* losso = pred + (size_t)BB * TT * DD;

    char* ws = (char*)d_ws;
    h4*       xwf    = (h4*)(ws + 0);                  // 268435456
    h4*       BhhV   = (h4*)(ws + 268435456);          //    262144
    h4*       BhhL   = (h4*)(ws + 268697600);          //    131072
    h4*       BhhS   = (h4*)(ws + 268828672);          //    131072
    _Float16* Bih    = (_Float16*)(ws + 268959744);    //    327680
    float*    pooled = (float*)(ws + 269287424);       //    524288
    float*    y0ws   = (float*)(ws + 269811712);       //    131072
    u32*      Wd1p   = (u32*)(ws + 269942784);         //     32768
    u32*      Wd2p   = (u32*)(ws + 269975552);         //     32768

    prep_kernel<<<480, 256, 0, stream>>>(W_hh, W_ih, Wd1, Wd2, BhhV, BhhL, BhhS, Bih, Wd1p, Wd2p);
    xw_kernel<<<2048, 256, 0, stream>>>(x, Bih, b_ih, b_hh, xwf);
    lstm_kernel<<<32, 512, 0, stream>>>((const h8*)BhhV, (const h8*)BhhL, (const h8*)BhhS,
                                        xwf, lengths, pooled);
    head_kernel<<<BB, 256, 0, stream>>>(pooled, Wp1, bp1, Wp2, bp2, y0ws);
    ode_kernel<<<BB, 256, 0, stream>>>(y0ws, Wd1p, bd1, Wd2p, bd2, ltime, lfeat, lmask, pred, losso);
}